// Round 2
// baseline (1665.543 us; speedup 1.0000x reference)
//
#include <hip/hip_runtime.h>

typedef unsigned short u16;
typedef unsigned int u32;
typedef float f32x4 __attribute__((ext_vector_type(4)));
typedef __bf16 bf16x8 __attribute__((ext_vector_type(8)));
typedef u16 u16x4 __attribute__((ext_vector_type(4)));

// B=256, T=512, FIN=128, H=256, 3H=768
#define TB 256
#define TT 512
#define TC 128  // T-chunk for the gemm2->gru pipeline

__device__ __forceinline__ u16 f2b(float f) {
  u32 x = __float_as_uint(f);
  return (u16)((x + 0x7fffu + ((x >> 16) & 1u)) >> 16);
}
__device__ __forceinline__ float blo(u32 u) { return __uint_as_float(u << 16); }
__device__ __forceinline__ float bhi(u32 u) { return __uint_as_float(u & 0xffff0000u); }

// ---------------- casts ----------------
__global__ void cast4_kernel(const float* __restrict__ in, u16* __restrict__ out, int n4) {
  int i = blockIdx.x * blockDim.x + threadIdx.x;
  for (; i < n4; i += gridDim.x * blockDim.x) {
    f32x4 v = ((const f32x4*)in)[i];
    u16x4 o = { f2b(v[0]), f2b(v[1]), f2b(v[2]), f2b(v[3]) };
    ((u16x4*)out)[i] = o;
  }
}

// in: (K,N) fp32 row-major -> out: (N,K) bf16 row-major (i.e. B^T for GEMM)
__global__ void tcast_kernel(const float* __restrict__ in, u16* __restrict__ out, int K, int N) {
  int idx = blockIdx.x * blockDim.x + threadIdx.x;
  if (idx < K * N) {
    int k = idx / N, n = idx % N;
    out[n * K + k] = f2b(in[idx]);
  }
}

// ---------------- GEMM: C = A @ B + bias, A bf16 row-major, Bt = B^T bf16 (N,K) ----------------
// 128x128 tile, BK=32, 4 waves each owning a 64x64 quadrant, mfma_f32_16x16x32_bf16.
// MODE 0: A rows = bm*128+r (dense), relu, C row-major ldc=256 (h1).
// MODE 1: A rows = bm*512 + t0 + r (T-chunk of batch bm), no relu, C[(bm*128+r)*768+n] (xg chunk).
template<int KT, int MODE>
__global__ __launch_bounds__(256) void gemm_bf16(const u16* __restrict__ A, const u16* __restrict__ Bt,
                                                 const float* __restrict__ bias, u16* __restrict__ C,
                                                 int t0) {
  constexpr int K = KT * 32;
  __shared__ u16 As[128 * 40];  // pad 32->40 shorts/row: conflict-free b128 frag reads
  __shared__ u16 Bs[128 * 40];
  const int tid = threadIdx.x;
  const int bm = blockIdx.x, bn = blockIdx.y;
  const int lane = tid & 63, wid = tid >> 6;
  const int l15 = lane & 15, l4 = lane >> 4;
  const int qm = (wid >> 1) * 64, qn = (wid & 1) * 64;

  const int c0 = tid, c1 = tid + 256;  // 16B chunks: chunk c covers LDS row c/4, k-elems (c%4)*8..+8
  const int ar0 = (MODE == 0) ? (bm * 128 + (c0 >> 2)) : (bm * 512 + t0 + (c0 >> 2));
  const int ar1 = (MODE == 0) ? (bm * 128 + (c1 >> 2)) : (bm * 512 + t0 + (c1 >> 2));
  const size_t ga0 = (size_t)ar0 * K + (c0 & 3) * 8;
  const size_t ga1 = (size_t)ar1 * K + (c1 & 3) * 8;
  const size_t gb0 = (size_t)(bn * 128 + (c0 >> 2)) * K + (c0 & 3) * 8;
  const size_t gb1 = (size_t)(bn * 128 + (c1 >> 2)) * K + (c1 & 3) * 8;
  const int sa0 = (c0 >> 2) * 40 + (c0 & 3) * 8;
  const int sa1 = (c1 >> 2) * 40 + (c1 & 3) * 8;

  uint4 ra0 = *(const uint4*)(A + ga0);
  uint4 ra1 = *(const uint4*)(A + ga1);
  uint4 rb0 = *(const uint4*)(Bt + gb0);
  uint4 rb1 = *(const uint4*)(Bt + gb1);

  f32x4 acc[4][4] = {};

  for (int kt = 0; kt < KT; ++kt) {
    __syncthreads();
    *(uint4*)(As + sa0) = ra0;
    *(uint4*)(As + sa1) = ra1;
    *(uint4*)(Bs + sa0) = rb0;
    *(uint4*)(Bs + sa1) = rb1;
    __syncthreads();
    if (kt + 1 < KT) {  // prefetch next tile into regs under the MFMA phase
      const int ko = (kt + 1) * 32;
      ra0 = *(const uint4*)(A + ga0 + ko);
      ra1 = *(const uint4*)(A + ga1 + ko);
      rb0 = *(const uint4*)(Bt + gb0 + ko);
      rb1 = *(const uint4*)(Bt + gb1 + ko);
    }
    bf16x8 af[4], bfr[4];
#pragma unroll
    for (int mt = 0; mt < 4; ++mt)
      af[mt] = *(const bf16x8*)(As + (qm + mt * 16 + l15) * 40 + l4 * 8);
#pragma unroll
    for (int nt = 0; nt < 4; ++nt)
      bfr[nt] = *(const bf16x8*)(Bs + (qn + nt * 16 + l15) * 40 + l4 * 8);
#pragma unroll
    for (int mt = 0; mt < 4; ++mt)
#pragma unroll
      for (int nt = 0; nt < 4; ++nt)
        acc[mt][nt] = __builtin_amdgcn_mfma_f32_16x16x32_bf16(af[mt], bfr[nt], acc[mt][nt], 0, 0, 0);
  }

#pragma unroll
  for (int mt = 0; mt < 4; ++mt) {
#pragma unroll
    for (int nt = 0; nt < 4; ++nt) {
      const int n = bn * 128 + qn + nt * 16 + l15;
      const float bv = bias[n];
#pragma unroll
      for (int j = 0; j < 4; ++j) {
        const int rloc = qm + mt * 16 + l4 * 4 + j;  // D: row=(lane>>4)*4+j, col=lane&15
        float v = acc[mt][nt][j] + bv;
        if (MODE == 0) {
          v = fmaxf(v, 0.f);
          C[(size_t)(bm * 128 + rloc) * 256 + n] = f2b(v);
        } else {
          C[((size_t)bm * 128 + rloc) * 768 + n] = f2b(v);
        }
      }
    }
  }
}

// ---------------- GRU chunk: 16 WGs x 512 threads; WG g owns batch rows 16g..16g+15. ----------------
// Processes TC steps; hidden state carried in global hstate (256x256 f32).
// Full Wr (bf16, as B-fragments) register-resident: wave w holds cols [96w,96w+96) = 48 frags = 192 VGPRs.
// xg chunk layout: (b, t_local, 768) -> per-batch t-sequential streaming.
__global__ __launch_bounds__(512) void gru_kernel(const u16* __restrict__ xgc, const u16* __restrict__ WrT,
                                                  const float* __restrict__ br, float* __restrict__ hstate,
                                                  int t0) {
  __shared__ float h_f[16 * 264];   // fp32 master h, pad 256->264
  __shared__ u16 h_b[16 * 264];     // bf16 copy (MFMA A-tile)
  __shared__ float recs[16 * 768];  // rec = h @ Wr exchange
  __shared__ float brs[768];
  const int tid = threadIdx.x;
  const int g = blockIdx.x;
  const int lane = tid & 63, wid = tid >> 6;
  const int l15 = lane & 15, l4 = lane >> 4;

  bf16x8 bw[8][6];
#pragma unroll
  for (int kk = 0; kk < 8; ++kk)
#pragma unroll
    for (int nt = 0; nt < 6; ++nt) {
      const int col = wid * 96 + nt * 16 + l15;
      bw[kk][nt] = *(const bf16x8*)(WrT + (size_t)col * 256 + kk * 32 + l4 * 8);
    }

  const int b = tid >> 5;          // local batch row 0..15
  const int c0 = (tid & 31) * 8;   // h-cols c0..c0+7

  if (t0 == 0) {
    for (int i = tid; i < 16 * 264; i += 512) { h_f[i] = 0.f; h_b[i] = 0; }
  } else {
    // restore carried state (every thread owns rows/cols disjointly: 16 rows x 32 col-groups)
    const float* hp = hstate + ((size_t)g * 16 + b) * 256 + c0;
    f32x4 v0 = *(const f32x4*)(hp);
    f32x4 v1 = *(const f32x4*)(hp + 4);
    *(f32x4*)(h_f + b * 264 + c0) = v0;
    *(f32x4*)(h_f + b * 264 + c0 + 4) = v1;
    u32 pk0 = (u32)f2b(v0[0]) | ((u32)f2b(v0[1]) << 16);
    u32 pk1 = (u32)f2b(v0[2]) | ((u32)f2b(v0[3]) << 16);
    u32 pk2 = (u32)f2b(v1[0]) | ((u32)f2b(v1[1]) << 16);
    u32 pk3 = (u32)f2b(v1[2]) | ((u32)f2b(v1[3]) << 16);
    *(uint4*)(h_b + b * 264 + c0) = make_uint4(pk0, pk1, pk2, pk3);
  }
  for (int i = tid; i < 768; i += 512) brs[i] = br[i];
  __syncthreads();

  for (int tl = 0; tl < TC; ++tl) {
    // prefetch this step's input-side gates (issued early, consumed after barrier)
    const u16* xp = xgc + ((size_t)(g * 16 + b) * TC + tl) * 768;
    const uint4 xzu = *(const uint4*)(xp + c0);
    const uint4 xru = *(const uint4*)(xp + 256 + c0);
    const uint4 xhu = *(const uint4*)(xp + 512 + c0);

    // rec = h @ Wr (wave's 96-col slice), M=16 = WG's batch rows
    f32x4 acc[6] = {};
#pragma unroll
    for (int kk = 0; kk < 8; ++kk) {
      const bf16x8 a = *(const bf16x8*)(h_b + l15 * 264 + kk * 32 + l4 * 8);
#pragma unroll
      for (int nt = 0; nt < 6; ++nt)
        acc[nt] = __builtin_amdgcn_mfma_f32_16x16x32_bf16(a, bw[kk][nt], acc[nt], 0, 0, 0);
    }
#pragma unroll
    for (int nt = 0; nt < 6; ++nt) {
      const int col = wid * 96 + nt * 16 + l15;
#pragma unroll
      for (int j = 0; j < 4; ++j)
        recs[(l4 * 4 + j) * 768 + col] = acc[nt][j];
    }
    __syncthreads();

    // gates: z=sig(xz+rz), r=sig(xr+rr), hh=relu(xh+r*rh), h=z*h+(1-z)*hh
    u32 pk[4];
#pragma unroll
    for (int half = 0; half < 2; ++half) {
      const int cc = c0 + 4 * half;
      f32x4 rz = *(const f32x4*)(recs + b * 768 + cc);
      f32x4 rr = *(const f32x4*)(recs + b * 768 + 256 + cc);
      f32x4 rh = *(const f32x4*)(recs + b * 768 + 512 + cc);
      rz += *(const f32x4*)(brs + cc);
      rr += *(const f32x4*)(brs + 256 + cc);
      rh += *(const f32x4*)(brs + 512 + cc);
      const u32 z0 = half ? xzu.z : xzu.x, z1 = half ? xzu.w : xzu.y;
      const u32 r0 = half ? xru.z : xru.x, r1 = half ? xru.w : xru.y;
      const u32 h0 = half ? xhu.z : xhu.x, h1 = half ? xhu.w : xhu.y;
      const f32x4 xzv = { blo(z0), bhi(z0), blo(z1), bhi(z1) };
      const f32x4 xrv = { blo(r0), bhi(r0), blo(r1), bhi(r1) };
      const f32x4 xhv = { blo(h0), bhi(h0), blo(h1), bhi(h1) };
      const f32x4 hov = *(const f32x4*)(h_f + b * 264 + cc);
      f32x4 hnv;
#pragma unroll
      for (int q = 0; q < 4; ++q) {
        const float z = 1.f / (1.f + __expf(-(xzv[q] + rz[q])));
        const float r = 1.f / (1.f + __expf(-(xrv[q] + rr[q])));
        const float hh = fmaxf(xhv[q] + r * rh[q], 0.f);
        hnv[q] = z * hov[q] + (1.f - z) * hh;
      }
      *(f32x4*)(h_f + b * 264 + cc) = hnv;
      pk[2 * half + 0] = (u32)f2b(hnv[0]) | ((u32)f2b(hnv[1]) << 16);
      pk[2 * half + 1] = (u32)f2b(hnv[2]) | ((u32)f2b(hnv[3]) << 16);
      if (tl == TC - 1)  // persist carried state for the next chunk
        *(f32x4*)(hstate + ((size_t)g * 16 + b) * 256 + cc) = hnv;
    }
    *(uint4*)(h_b + b * 264 + c0) = make_uint4(pk[0], pk[1], pk[2], pk[3]);
    __syncthreads();
  }
}

// ---------------- output: y = [h,h] @ W2 + b2 = h @ (W2_top + W2_bot) + b2 ----------------
__global__ void out_kernel(const float* __restrict__ h, const float* __restrict__ W2,
                           const float* __restrict__ b2, float* __restrict__ y) {
  const int bb = blockIdx.x, j = threadIdx.x;  // 256 blocks x 128 threads
  const float* hr = h + (size_t)bb * 256;
  float s = b2[j];
  for (int i = 0; i < 256; ++i)
    s = fmaf(hr[i], W2[i * 128 + j] + W2[(i + 256) * 128 + j], s);
  y[(size_t)bb * 128 + j] = s;
}

extern "C" void kernel_launch(void* const* d_in, const int* in_sizes, int n_in,
                              void* d_out, int out_size, void* d_ws, size_t ws_size,
                              hipStream_t stream) {
  const float* x  = (const float*)d_in[0];
  const float* W1 = (const float*)d_in[1];
  const float* b1 = (const float*)d_in[2];
  const float* Wk = (const float*)d_in[3];
  const float* Wr = (const float*)d_in[4];
  const float* bi = (const float*)d_in[5];
  const float* br = (const float*)d_in[6];
  const float* W2 = (const float*)d_in[7];
  const float* b2 = (const float*)d_in[8];
  float* y = (float*)d_out;

  // workspace layout: 118,554,624 bytes total. x_bf overlays the chunk buffer
  // (dead before the first gemm2 chunk runs).
  const size_t NEED = 67108864ull + 50331648ull + 65536ull + 393216ull + 393216ull + 262144ull;
  if (ws_size < NEED) return;  // diagnostic: clean absmax-fail (=stub value) => ws too small

  char* ws = (char*)d_ws;
  u16* h1    = (u16*)ws;  ws += 67108864;   // (131072,256) bf16
  u16* xgc   = (u16*)ws;  ws += 50331648;   // (256,128,768) bf16 chunk; xb overlay
  u16* W1T   = (u16*)ws;  ws += 65536;      // (256,128) bf16
  u16* WkT   = (u16*)ws;  ws += 393216;     // (768,256) bf16
  u16* WrT   = (u16*)ws;  ws += 393216;     // (768,256) bf16
  float* hstate = (float*)ws;               // (256,256) f32 carried GRU state
  u16* xb    = xgc;                         // (131072,128) bf16 overlay

  cast4_kernel<<<2048, 256, 0, stream>>>(x, xb, 16777216 / 4);
  tcast_kernel<<<128, 256, 0, stream>>>(W1, W1T, 128, 256);
  tcast_kernel<<<768, 256, 0, stream>>>(Wk, WkT, 256, 768);
  tcast_kernel<<<768, 256, 0, stream>>>(Wr, WrT, 256, 768);
  gemm_bf16<4, 0><<<dim3(1024, 2), 256, 0, stream>>>(xb, W1T, b1, h1, 0);
  for (int c = 0; c < TT / TC; ++c) {
    gemm_bf16<8, 1><<<dim3(256, 6), 256, 0, stream>>>(h1, WkT, bi, xgc, c * TC);
    gru_kernel<<<16, 512, 0, stream>>>(xgc, WrT, br, hstate, c * TC);
  }
  out_kernel<<<256, 128, 0, stream>>>(hstate, W2, b2, y);
}

// Round 3
// 1571.836 us; speedup vs baseline: 1.0596x; 1.0596x over previous
//
#include <hip/hip_runtime.h>

typedef unsigned short u16;
typedef unsigned int u32;
typedef float f32x4 __attribute__((ext_vector_type(4)));
typedef __bf16 bf16x8 __attribute__((ext_vector_type(8)));
typedef u16 u16x4 __attribute__((ext_vector_type(4)));

// B=256, T=512, FIN=128, H=256, 3H=768
#define TB 256
#define TT 512
#define TC 128  // T-chunk for the gemm2->gru pipeline

__device__ __forceinline__ u16 f2b(float f) {
  u32 x = __float_as_uint(f);
  return (u16)((x + 0x7fffu + ((x >> 16) & 1u)) >> 16);
}
__device__ __forceinline__ float blo(u32 u) { return __uint_as_float(u << 16); }
__device__ __forceinline__ float bhi(u32 u) { return __uint_as_float(u & 0xffff0000u); }
__device__ __forceinline__ float sigm(float x) {
  return __builtin_amdgcn_rcpf(1.f + __expf(-x));
}

// ---------------- casts ----------------
__global__ void cast4_kernel(const float* __restrict__ in, u16* __restrict__ out, int n4) {
  int i = blockIdx.x * blockDim.x + threadIdx.x;
  for (; i < n4; i += gridDim.x * blockDim.x) {
    f32x4 v = ((const f32x4*)in)[i];
    u16x4 o = { f2b(v[0]), f2b(v[1]), f2b(v[2]), f2b(v[3]) };
    ((u16x4*)out)[i] = o;
  }
}

// in: (K,N) fp32 row-major -> out: (N,K) bf16 row-major (B^T for GEMM)
__global__ void tcast_kernel(const float* __restrict__ in, u16* __restrict__ out, int K, int N) {
  int idx = blockIdx.x * blockDim.x + threadIdx.x;
  if (idx < K * N) {
    int k = idx / N, n = idx % N;
    out[n * K + k] = f2b(in[idx]);
  }
}

// Wr (256,768) -> permuted B^T: pcol(w,nt,l15) holds original col n = gate*256 + 32w + 2*l15 + grp,
// nt = gate*2+grp. Wave w then owns gate triples (z,r,h) for h-cols {32w+2*l15+grp}.
__global__ void wrperm_kernel(const float* __restrict__ in, u16* __restrict__ out) {
  int idx = blockIdx.x * blockDim.x + threadIdx.x;  // over 256*768, k-major rows
  if (idx < 256 * 768) {
    int k = idx / 768, n = idx % 768;
    int gate = n >> 8, c = n & 255;
    int w = c >> 5, cc = c & 31, l15 = cc >> 1, grp = cc & 1;
    int nt = gate * 2 + grp;
    out[((((w * 6 + nt) << 4) + l15) << 8) + k] = f2b(in[idx]);
  }
}

// biasMod = bi + [br_z, br_r, 0]: fold recurrent bias for z,r into the input-side GEMM
__global__ void biasmod_kernel(const float* __restrict__ bi, const float* __restrict__ br,
                               float* __restrict__ bm) {
  int n = blockIdx.x * blockDim.x + threadIdx.x;
  if (n < 768) bm[n] = bi[n] + (n < 512 ? br[n] : 0.f);
}

// ---------------- GEMM: C = A @ B + bias, A bf16 row-major, Bt = B^T bf16 (N,K) ----------------
// 128x128 tile, BK=32, 4 waves each owning a 64x64 quadrant, mfma_f32_16x16x32_bf16.
// MODE 0: A rows = bm*128+r (dense), relu, C row-major ldc=256 (h1).
// MODE 1: A rows = bm*512 + t0 + r (T-chunk of batch bm), no relu,
//         C scattered into the GRU lane layout:
//         idx = ((t*16+g)*8+wid)*1536 + (l15*4+l4)*24 + nt*4 + j
//         from (b=bm, t=r, n): g=b>>4, bl=b&15, l4=bl>>2, j=bl&3;
//         gate=n>>8, c=n&255, wid=c>>5, l15=(c&31)>>1, nt=gate*2+(c&1).
template<int KT, int MODE>
__global__ __launch_bounds__(256) void gemm_bf16(const u16* __restrict__ A, const u16* __restrict__ Bt,
                                                 const float* __restrict__ bias, u16* __restrict__ C,
                                                 int t0) {
  constexpr int K = KT * 32;
  __shared__ u16 As[128 * 40];  // pad 32->40 shorts/row: conflict-free b128 frag reads
  __shared__ u16 Bs[128 * 40];
  const int tid = threadIdx.x;
  const int bm = blockIdx.x, bn = blockIdx.y;
  const int lane = tid & 63, wid = tid >> 6;
  const int l15 = lane & 15, l4 = lane >> 4;
  const int qm = (wid >> 1) * 64, qn = (wid & 1) * 64;

  const int c0 = tid, c1 = tid + 256;  // 16B chunks: chunk c covers LDS row c/4, k-elems (c%4)*8..+8
  const int ar0 = (MODE == 0) ? (bm * 128 + (c0 >> 2)) : (bm * 512 + t0 + (c0 >> 2));
  const int ar1 = (MODE == 0) ? (bm * 128 + (c1 >> 2)) : (bm * 512 + t0 + (c1 >> 2));
  const size_t ga0 = (size_t)ar0 * K + (c0 & 3) * 8;
  const size_t ga1 = (size_t)ar1 * K + (c1 & 3) * 8;
  const size_t gb0 = (size_t)(bn * 128 + (c0 >> 2)) * K + (c0 & 3) * 8;
  const size_t gb1 = (size_t)(bn * 128 + (c1 >> 2)) * K + (c1 & 3) * 8;
  const int sa0 = (c0 >> 2) * 40 + (c0 & 3) * 8;
  const int sa1 = (c1 >> 2) * 40 + (c1 & 3) * 8;

  uint4 ra0 = *(const uint4*)(A + ga0);
  uint4 ra1 = *(const uint4*)(A + ga1);
  uint4 rb0 = *(const uint4*)(Bt + gb0);
  uint4 rb1 = *(const uint4*)(Bt + gb1);

  f32x4 acc[4][4] = {};

  for (int kt = 0; kt < KT; ++kt) {
    __syncthreads();
    *(uint4*)(As + sa0) = ra0;
    *(uint4*)(As + sa1) = ra1;
    *(uint4*)(Bs + sa0) = rb0;
    *(uint4*)(Bs + sa1) = rb1;
    __syncthreads();
    if (kt + 1 < KT) {  // prefetch next tile into regs under the MFMA phase
      const int ko = (kt + 1) * 32;
      ra0 = *(const uint4*)(A + ga0 + ko);
      ra1 = *(const uint4*)(A + ga1 + ko);
      rb0 = *(const uint4*)(Bt + gb0 + ko);
      rb1 = *(const uint4*)(Bt + gb1 + ko);
    }
    bf16x8 af[4], bfr[4];
#pragma unroll
    for (int mt = 0; mt < 4; ++mt)
      af[mt] = *(const bf16x8*)(As + (qm + mt * 16 + l15) * 40 + l4 * 8);
#pragma unroll
    for (int nt = 0; nt < 4; ++nt)
      bfr[nt] = *(const bf16x8*)(Bs + (qn + nt * 16 + l15) * 40 + l4 * 8);
#pragma unroll
    for (int mt = 0; mt < 4; ++mt)
#pragma unroll
      for (int nt = 0; nt < 4; ++nt)
        acc[mt][nt] = __builtin_amdgcn_mfma_f32_16x16x32_bf16(af[mt], bfr[nt], acc[mt][nt], 0, 0, 0);
  }

#pragma unroll
  for (int mt = 0; mt < 4; ++mt) {
#pragma unroll
    for (int nt = 0; nt < 4; ++nt) {
      const int n = bn * 128 + qn + nt * 16 + l15;
      const float bv = bias[n];
#pragma unroll
      for (int j = 0; j < 4; ++j) {
        const int rloc = qm + mt * 16 + l4 * 4 + j;  // D: row=(lane>>4)*4+j, col=lane&15
        float v = acc[mt][nt][j] + bv;
        if (MODE == 0) {
          v = fmaxf(v, 0.f);
          C[(size_t)(bm * 128 + rloc) * 256 + n] = f2b(v);
        } else {
          const int gate = n >> 8, cc = n & 255;
          const int widc = cc >> 5, l15c = (cc & 31) >> 1, grpc = cc & 1;
          const int ntc = gate * 2 + grpc;
          const int gg = bm >> 4, bl = bm & 15;
          const size_t idx = (((size_t)rloc * 16 + gg) * 8 + widc) * 1536 +
                             (l15c * 4 + (bl >> 2)) * 24 + ntc * 4 + (bl & 3);
          C[idx] = f2b(v);
        }
      }
    }
  }
}

// ---------------- GRU chunk: 16 WGs x 512 threads (8 waves); WG g owns batch rows 16g..16g+15 ---
// Wave wid holds the permuted Wr B-fragments for its 32 h-cols x 3 gates in 192 VGPRs
// (launch_bounds(512,2) caps at 2 waves/SIMD => 256 regs, no spill). Gates computed entirely
// in-register on the accumulator lanes; only the bf16 h matrix (8.4KB x2 ping-pong) goes
// through LDS; one barrier per step.
__global__ __launch_bounds__(512, 2) void gru_kernel(const u16* __restrict__ xgc,
                                                     const u16* __restrict__ WrP,
                                                     const float* __restrict__ br,
                                                     float* __restrict__ hstate, int t0) {
  __shared__ u16 hb0[16 * 264];  // h bf16, [row][col], stride 264 (pad) - ping
  __shared__ u16 hb1[16 * 264];  // pong
  const int tid = threadIdx.x, g = blockIdx.x;
  const int lane = tid & 63, wid = tid >> 6;
  const int l15 = lane & 15, l4 = lane >> 4;

  // register-resident Wr fragments: wave wid covers permuted cols [wid*96, wid*96+96)
  bf16x8 bw[8][6];
#pragma unroll
  for (int kk = 0; kk < 8; ++kk)
#pragma unroll
    for (int nt = 0; nt < 6; ++nt)
      bw[kk][nt] = *(const bf16x8*)(WrP + ((((wid * 6 + nt) << 4) + l15) << 8) + kk * 32 + l4 * 8);

  const int cbase = wid * 32 + l15 * 2;      // this lane's h-col pair (natural order)
  const float brh0 = br[512 + cbase];
  const float brh1 = br[512 + cbase + 1];
  const int hoff = wid * 32 + l15 * 2;       // u16 offset within an h_b row

  f32x4 h0, h1;  // fp32 master h: h{grp}[j] for rows l4*4+j
  if (t0 == 0) {
    h0 = {0.f, 0.f, 0.f, 0.f};
    h1 = {0.f, 0.f, 0.f, 0.f};
  } else {
#pragma unroll
    for (int j = 0; j < 4; ++j) {
      float2 ld = *(const float2*)(hstate + ((size_t)g * 16 + l4 * 4 + j) * 256 + cbase);
      h0[j] = ld.x; h1[j] = ld.y;
    }
  }
#pragma unroll
  for (int j = 0; j < 4; ++j)
    *(u32*)(hb0 + (l4 * 4 + j) * 264 + hoff) = (u32)f2b(h0[j]) | ((u32)f2b(h1[j]) << 16);
  __syncthreads();

  // per-lane xg base: layout [t][g][wid][l15][l4][nt(6)][j(4)] bf16 (48B contiguous per lane)
  const u16* xp = xgc + ((size_t)g * 8 + wid) * 1536 + (l15 * 4 + l4) * 24;

#define GRU_STEP(SRC, DST, TL)                                                                  \
  {                                                                                             \
    const u16* xq = xp + (size_t)(TL) * 196608;                                                 \
    const uint4 xzq = *(const uint4*)(xq);        /* z: grp0 j0-3, grp1 j0-3 */                 \
    const uint2 xrq = *(const uint2*)(xq + 8);    /* r: grp0 j0-1... packed same */             \
    const uint2 xrq2 = *(const uint2*)(xq + 12);                                                \
    const uint2 xhq = *(const uint2*)(xq + 16);                                                 \
    const uint2 xhq2 = *(const uint2*)(xq + 20);                                                \
    f32x4 acc[6] = {};                                                                          \
    _Pragma("unroll")                                                                           \
    for (int kk = 0; kk < 8; ++kk) {                                                            \
      const bf16x8 a = *(const bf16x8*)((SRC) + l15 * 264 + kk * 32 + l4 * 8);                  \
      _Pragma("unroll")                                                                         \
      for (int nt = 0; nt < 6; ++nt)                                                            \
        acc[nt] = __builtin_amdgcn_mfma_f32_16x16x32_bf16(a, bw[kk][nt], acc[nt], 0, 0, 0);     \
    }                                                                                           \
    _Pragma("unroll")                                                                           \
    for (int j = 0; j < 4; ++j) {                                                               \
      const u32 wz0 = (j >> 1) ? xzq.y : xzq.x;                                                 \
      const u32 wz1 = (j >> 1) ? xzq.w : xzq.z;                                                 \
      const u32 wr0 = (j >> 1) ? xrq.y : xrq.x;                                                 \
      const u32 wr1 = (j >> 1) ? xrq2.y : xrq2.x;                                               \
      const u32 wh0 = (j >> 1) ? xhq.y : xhq.x;                                                 \
      const u32 wh1 = (j >> 1) ? xhq2.y : xhq2.x;                                               \
      const float xz0 = (j & 1) ? bhi(wz0) : blo(wz0);                                          \
      const float xz1 = (j & 1) ? bhi(wz1) : blo(wz1);                                          \
      const float xr0 = (j & 1) ? bhi(wr0) : blo(wr0);                                          \
      const float xr1 = (j & 1) ? bhi(wr1) : blo(wr1);                                          \
      const float xh0 = (j & 1) ? bhi(wh0) : blo(wh0);                                          \
      const float xh1 = (j & 1) ? bhi(wh1) : blo(wh1);                                          \
      const float z0 = sigm(xz0 + acc[0][j]);                                                   \
      const float z1 = sigm(xz1 + acc[1][j]);                                                   \
      const float r0 = sigm(xr0 + acc[2][j]);                                                   \
      const float r1 = sigm(xr1 + acc[3][j]);                                                   \
      const float hh0 = fmaxf(fmaf(r0, acc[4][j] + brh0, xh0), 0.f);                            \
      const float hh1 = fmaxf(fmaf(r1, acc[5][j] + brh1, xh1), 0.f);                            \
      h0[j] = fmaf(z0, h0[j] - hh0, hh0);                                                       \
      h1[j] = fmaf(z1, h1[j] - hh1, hh1);                                                       \
      *(u32*)((DST) + (l4 * 4 + j) * 264 + hoff) = (u32)f2b(h0[j]) | ((u32)f2b(h1[j]) << 16);   \
    }                                                                                           \
    __syncthreads();                                                                            \
  }

  for (int tl = 0; tl < TC; tl += 2) {
    GRU_STEP(hb0, hb1, tl);
    GRU_STEP(hb1, hb0, tl + 1);
  }
#undef GRU_STEP

  // persist carried state (lanes own disjoint (row, colpair) slots)
#pragma unroll
  for (int j = 0; j < 4; ++j) {
    float2 st = {h0[j], h1[j]};
    *(float2*)(hstate + ((size_t)g * 16 + l4 * 4 + j) * 256 + cbase) = st;
  }
}

// ---------------- output: y = [h,h] @ W2 + b2 = h @ (W2_top + W2_bot) + b2 ----------------
__global__ void out_kernel(const float* __restrict__ h, const float* __restrict__ W2,
                           const float* __restrict__ b2, float* __restrict__ y) {
  const int bb = blockIdx.x, j = threadIdx.x;  // 256 blocks x 128 threads
  const float* hr = h + (size_t)bb * 256;
  float s = b2[j];
  for (int i = 0; i < 256; ++i)
    s = fmaf(hr[i], W2[i * 128 + j] + W2[(i + 256) * 128 + j], s);
  y[(size_t)bb * 128 + j] = s;
}

extern "C" void kernel_launch(void* const* d_in, const int* in_sizes, int n_in,
                              void* d_out, int out_size, void* d_ws, size_t ws_size,
                              hipStream_t stream) {
  const float* x  = (const float*)d_in[0];
  const float* W1 = (const float*)d_in[1];
  const float* b1 = (const float*)d_in[2];
  const float* Wk = (const float*)d_in[3];
  const float* Wr = (const float*)d_in[4];
  const float* bi = (const float*)d_in[5];
  const float* br = (const float*)d_in[6];
  const float* W2 = (const float*)d_in[7];
  const float* b2 = (const float*)d_in[8];
  float* y = (float*)d_out;

  // workspace: 118.6 MB total; x_bf overlays the xg chunk buffer (dead before gemm2 runs)
  const size_t NEED = 67108864ull + 50331648ull + 65536ull + 393216ull + 393216ull + 262144ull + 4096ull;
  if (ws_size < NEED) return;

  char* ws = (char*)d_ws;
  u16* h1    = (u16*)ws;  ws += 67108864;   // (131072,256) bf16
  u16* xgc   = (u16*)ws;  ws += 50331648;   // xg chunk (GRU lane layout); xb overlay
  u16* W1T   = (u16*)ws;  ws += 65536;      // (256,128) bf16
  u16* WkT   = (u16*)ws;  ws += 393216;     // (768,256) bf16
  u16* WrP   = (u16*)ws;  ws += 393216;     // permuted Wr^T (768,256) bf16
  float* hstate = (float*)ws; ws += 262144; // (256,256) f32 carried GRU state
  float* biasM  = (float*)ws;               // 768 f32
  u16* xb    = xgc;                         // (131072,128) bf16 overlay

  cast4_kernel<<<2048, 256, 0, stream>>>(x, xb, 16777216 / 4);
  tcast_kernel<<<128, 256, 0, stream>>>(W1, W1T, 128, 256);
  tcast_kernel<<<768, 256, 0, stream>>>(Wk, WkT, 256, 768);
  wrperm_kernel<<<768, 256, 0, stream>>>(Wr, WrP);
  biasmod_kernel<<<3, 256, 0, stream>>>(bi, br, biasM);
  gemm_bf16<4, 0><<<dim3(1024, 2), 256, 0, stream>>>(xb, W1T, b1, h1, 0);
  for (int c = 0; c < TT / TC; ++c) {
    gemm_bf16<8, 1><<<dim3(256, 6), 256, 0, stream>>>(h1, WkT, biasM, xgc, c * TC);
    gru_kernel<<<16, 512, 0, stream>>>(xgc, WrP, br, hstate, c * TC);
  }
  out_kernel<<<256, 128, 0, stream>>>(hstate, W2, b2, y);
}